// Round 1
// baseline (170.793 us; speedup 1.0000x reference)
//
#include <hip/hip_runtime.h>
#include <stdint.h>

#define BB 8
#define NSQ 262144   // 512*512
#define TT 1024
#define FF 8

using ull = unsigned long long;

// Order-preserving float->uint key; packed with element index so min() matches
// stable argsort's first-occurrence-of-minimum.
__device__ inline ull pack_key(float v, unsigned idx) {
    unsigned u = __float_as_uint(v);
    unsigned key = (u & 0x80000000u) ? ~u : (u | 0x80000000u);
    return ((ull)key << 32) | (ull)idx;
}

__global__ __launch_bounds__(256) void hist_kernel(
    const float* __restrict__ inp, const float* __restrict__ bins,
    const float* __restrict__ wts,
    float* __restrict__ partG, unsigned* __restrict__ partCnt,
    ull* __restrict__ partMin, int P, int epb)
{
    __shared__ float sbins[TT];          // 4 KB
    __shared__ float sG[TT * FF];        // 32 KB
    __shared__ unsigned sCnt[TT];        // 4 KB
    __shared__ ull sMinW[4];

    int blk = blockIdx.x;
    int b = blk / P, p = blk % P;
    int tid = threadIdx.x;

    for (int i = tid; i < TT * FF; i += 256) sG[i] = 0.f;
    for (int i = tid; i < TT; i += 256) { sCnt[i] = 0u; sbins[i] = bins[b * TT + i]; }
    __syncthreads();

    size_t base = (size_t)b * NSQ + (size_t)p * epb;
    ull lmin = ~0ull;
    for (int e = tid; e < epb; e += 256) {
        float v = inp[base + e];
        ull k64 = pack_key(v, (unsigned)(p * epb + e));
        if (k64 < lmin) lmin = k64;
        // upper_bound: first index with bins[idx] > v  (so prefix over buckets
        // k<=j counts exactly the elements with v < bins[j])
        int lo = 0, hi = TT;
        #pragma unroll
        for (int it = 0; it < 10; ++it) {
            int mid = (lo + hi) >> 1;
            if (sbins[mid] <= v) lo = mid + 1; else hi = mid;
        }
        if (lo < TT) {
            atomicAdd(&sCnt[lo], 1u);
            const float4* wp = (const float4*)(wts + (base + (size_t)e) * FF);
            float4 w0 = wp[0], w1 = wp[1];
            float* gp = &sG[lo * FF];
            atomicAdd(gp + 0, w0.x); atomicAdd(gp + 1, w0.y);
            atomicAdd(gp + 2, w0.z); atomicAdd(gp + 3, w0.w);
            atomicAdd(gp + 4, w1.x); atomicAdd(gp + 5, w1.y);
            atomicAdd(gp + 6, w1.z); atomicAdd(gp + 7, w1.w);
        }
    }
    // block min reduce (wave shuffle, then across 4 waves)
    int lane = tid & 63, wv = tid >> 6;
    for (int off = 32; off > 0; off >>= 1) {
        unsigned hi32 = (unsigned)(lmin >> 32), lo32 = (unsigned)(lmin & 0xFFFFFFFFu);
        unsigned ohi = __shfl_down(hi32, off, 64);
        unsigned olo = __shfl_down(lo32, off, 64);
        ull other = ((ull)ohi << 32) | (ull)olo;
        if (other < lmin) lmin = other;
    }
    if (lane == 0) sMinW[wv] = lmin;
    __syncthreads();
    if (tid == 0) {
        ull m = sMinW[0];
        for (int w = 1; w < 4; ++w) if (sMinW[w] < m) m = sMinW[w];
        partMin[(size_t)p * BB + b] = m;
    }
    // write partials: layout [P][B][T][F] so the reduce kernel is coalesced per p-slice
    size_t gbase = ((size_t)p * BB + b) * (size_t)(TT * FF);
    for (int i = tid; i < TT * FF; i += 256) partG[gbase + i] = sG[i];
    size_t cbase = ((size_t)p * BB + b) * (size_t)TT;
    for (int i = tid; i < TT; i += 256) partCnt[cbase + i] = sCnt[i];
}

__global__ __launch_bounds__(256) void reduce_kernel(
    const float* __restrict__ partG, const unsigned* __restrict__ partCnt,
    float* __restrict__ redG, float* __restrict__ redCnt, int P)
{
    int idx = blockIdx.x * blockDim.x + threadIdx.x;
    if (idx < BB * TT * FF) {
        float s = 0.f;
        for (int p = 0; p < P; ++p) s += partG[(size_t)p * (BB * TT * FF) + idx];
        redG[idx] = s;
    }
    if (idx < BB * TT) {
        unsigned c = 0;
        for (int p = 0; p < P; ++p) c += partCnt[(size_t)p * (BB * TT) + idx];
        redCnt[idx] = (float)c;   // counts <= 2^18, exact in f32
    }
}

__global__ __launch_bounds__(1024) void finalize_kernel(
    const float* __restrict__ redG, const float* __restrict__ redCnt,
    const ull* __restrict__ partMin, const float* __restrict__ wts,
    float* __restrict__ out, int P)
{
    int b = blockIdx.x, j = threadIdx.x;
    __shared__ float buf[2][TT];
    __shared__ float scnt[TT];
    __shared__ float wmin[FF];
    __shared__ unsigned sMinIdx;

    if (j == 0) {
        ull m = ~0ull;
        for (int p = 0; p < P; ++p) {
            ull v = partMin[(size_t)p * BB + b];
            if (v < m) m = v;
        }
        sMinIdx = (unsigned)(m & 0xFFFFFFFFu);
    }
    __syncthreads();
    if (j < FF) wmin[j] = wts[((size_t)b * NSQ + sMinIdx) * FF + j];

    // inclusive scan of counts (Hillis-Steele, double-buffered)
    buf[0][j] = redCnt[b * TT + j];
    __syncthreads();
    int cur = 0;
    for (int off = 1; off < TT; off <<= 1) {
        float v = buf[cur][j];
        if (j >= off) v += buf[cur][j - off];
        buf[cur ^ 1][j] = v;
        cur ^= 1;
        __syncthreads();
    }
    scnt[j] = buf[cur][j];
    __syncthreads();

    for (int f = 0; f < FF; ++f) {
        buf[0][j] = redG[((size_t)b * TT + j) * FF + f];
        cur = 0;
        __syncthreads();
        for (int off = 1; off < TT; off <<= 1) {
            float v = buf[cur][j];
            if (j >= off) v += buf[cur][j - off];
            buf[cur ^ 1][j] = v;
            cur ^= 1;
            __syncthreads();
        }
        float Cj   = buf[cur][j];
        float Cjm1 = (j > 0) ? buf[cur][j - 1] : 0.f;
        // reference quirk: idx = clip(counts-1, 0) -> counts==0 gathers
        // cumsum_w[0] == weight of the minimum element, not 0
        float csj   = (scnt[j] == 0.f) ? wmin[f] : Cj;
        float csjm1 = (j == 0) ? 0.f
                     : ((scnt[j - 1] == 0.f) ? wmin[f] : Cjm1);
        out[((size_t)b * TT + j) * FF + f] = csj - csjm1;
        __syncthreads();
    }
}

extern "C" void kernel_launch(void* const* d_in, const int* in_sizes, int n_in,
                              void* d_out, int out_size, void* d_ws, size_t ws_size,
                              hipStream_t stream)
{
    const float* inp  = (const float*)d_in[0];
    const float* bins = (const float*)d_in[1];
    const float* wts  = (const float*)d_in[2];
    float* out = (float*)d_out;

    // pick partial-count P to fit workspace (power of two, divides 262144)
    int P = 64;
    for (;;) {
        size_t need = (size_t)P * BB * TT * FF * 4   // partG
                    + (size_t)P * BB * TT * 4        // partCnt
                    + (size_t)P * BB * 8             // partMin
                    + (size_t)BB * TT * FF * 4       // redG
                    + (size_t)BB * TT * 4            // redCnt
                    + 1024;
        if (need <= ws_size || P == 1) break;
        P >>= 1;
    }

    char* w = (char*)d_ws;
    float*    partG   = (float*)w;    w += (size_t)P * BB * TT * FF * 4;
    unsigned* partCnt = (unsigned*)w; w += (size_t)P * BB * TT * 4;
    ull*      partMin = (ull*)w;      w += (size_t)P * BB * 8;
    float*    redG    = (float*)w;    w += (size_t)BB * TT * FF * 4;
    float*    redCnt  = (float*)w;

    int epb = NSQ / P;
    hist_kernel<<<dim3(BB * P), dim3(256), 0, stream>>>(
        inp, bins, wts, partG, partCnt, partMin, P, epb);
    reduce_kernel<<<dim3((BB * TT * FF + 255) / 256), dim3(256), 0, stream>>>(
        partG, partCnt, redG, redCnt, P);
    finalize_kernel<<<dim3(BB), dim3(TT), 0, stream>>>(
        redG, redCnt, partMin, wts, out, P);
}

// Round 2
// 154.031 us; speedup vs baseline: 1.1088x; 1.1088x over previous
//
#include <hip/hip_runtime.h>
#include <stdint.h>

#define BB 8
#define NSQ 262144   // 512*512
#define TT 1024
#define FF 8
#define CH 9         // 8 weight features + 1 count channel (exact in f32, counts < 2^24)

using ull = unsigned long long;

// Order-preserving float->uint key packed with element index so min() matches
// stable argsort's first-occurrence-of-minimum.
__device__ inline ull pack_key(float v, unsigned idx) {
    unsigned u = __float_as_uint(v);
    unsigned key = (u & 0x80000000u) ? ~u : (u | 0x80000000u);
    return ((ull)key << 32) | (ull)idx;
}

// LDS: sbins 4 KB + sG 36 KB = 40960 B exactly -> 4 blocks/CU (160 KB LDS).
// launch_bounds(256,4): 4 waves/EU min -> VGPR capped at 128 -> occupancy holds.
__global__ __launch_bounds__(256, 4) void hist_kernel(
    const float* __restrict__ inp, const float* __restrict__ bins,
    const float* __restrict__ wts,
    float* __restrict__ part,      // [B][CH][P][T]
    ull* __restrict__ partMin,     // [P][B]
    int P, int iters)
{
    __shared__ float sbins[TT];
    __shared__ float sG[TT * CH];

    int blk = blockIdx.x;
    int b = blk / P, p = blk % P;
    int tid = threadIdx.x;

    for (int i = tid; i < TT * CH; i += 256) sG[i] = 0.f;
    for (int i = tid; i < TT; i += 256) sbins[i] = bins[b * TT + i];
    __syncthreads();

    int epb = iters * 1024;                 // elements per block
    int e_base = p * epb;                   // element offset within batch
    const float4* inp4 = (const float4*)(inp + (size_t)b * NSQ + e_base);
    const float4* wp   = (const float4*)(wts + ((size_t)b * NSQ + e_base) * FF);

    ull lmin = ~0ull;
    for (int it = 0; it < iters; ++it) {
        int q = it * 256 + tid;             // float4 index within block's range
        float4 v = inp4[q];
        // prefetch all 4 elements' weights (8x float4 = 32 VGPRs); compiler
        // keeps these in flight under the binary searches.
        float4 w0a = wp[q*8+0], w0b = wp[q*8+1];
        float4 w1a = wp[q*8+2], w1b = wp[q*8+3];
        float4 w2a = wp[q*8+4], w2b = wp[q*8+5];
        float4 w3a = wp[q*8+6], w3b = wp[q*8+7];

        // 4 independent upper_bound searches, interleaved (4x ILP on the
        // dependent LDS-read chain). upper_bound: first idx with bins[idx] > v.
        int lo0 = 0, hi0 = TT, lo1 = 0, hi1 = TT;
        int lo2 = 0, hi2 = TT, lo3 = 0, hi3 = TT;
        #pragma unroll
        for (int lev = 0; lev < 10; ++lev) {
            int m0 = (lo0 + hi0) >> 1, m1 = (lo1 + hi1) >> 1;
            int m2 = (lo2 + hi2) >> 1, m3 = (lo3 + hi3) >> 1;
            float b0 = sbins[m0], b1 = sbins[m1], b2 = sbins[m2], b3 = sbins[m3];
            if (b0 <= v.x) lo0 = m0 + 1; else hi0 = m0;
            if (b1 <= v.y) lo1 = m1 + 1; else hi1 = m1;
            if (b2 <= v.z) lo2 = m2 + 1; else hi2 = m2;
            if (b3 <= v.w) lo3 = m3 + 1; else hi3 = m3;
        }

        unsigned e0 = (unsigned)(e_base + q * 4);
        lmin = min(lmin, pack_key(v.x, e0 + 0));
        lmin = min(lmin, pack_key(v.y, e0 + 1));
        lmin = min(lmin, pack_key(v.z, e0 + 2));
        lmin = min(lmin, pack_key(v.w, e0 + 3));

        if (lo0 < TT) {
            float* gp = &sG[lo0 * CH];
            atomicAdd(gp+0, w0a.x); atomicAdd(gp+1, w0a.y);
            atomicAdd(gp+2, w0a.z); atomicAdd(gp+3, w0a.w);
            atomicAdd(gp+4, w0b.x); atomicAdd(gp+5, w0b.y);
            atomicAdd(gp+6, w0b.z); atomicAdd(gp+7, w0b.w);
            atomicAdd(gp+8, 1.0f);
        }
        if (lo1 < TT) {
            float* gp = &sG[lo1 * CH];
            atomicAdd(gp+0, w1a.x); atomicAdd(gp+1, w1a.y);
            atomicAdd(gp+2, w1a.z); atomicAdd(gp+3, w1a.w);
            atomicAdd(gp+4, w1b.x); atomicAdd(gp+5, w1b.y);
            atomicAdd(gp+6, w1b.z); atomicAdd(gp+7, w1b.w);
            atomicAdd(gp+8, 1.0f);
        }
        if (lo2 < TT) {
            float* gp = &sG[lo2 * CH];
            atomicAdd(gp+0, w2a.x); atomicAdd(gp+1, w2a.y);
            atomicAdd(gp+2, w2a.z); atomicAdd(gp+3, w2a.w);
            atomicAdd(gp+4, w2b.x); atomicAdd(gp+5, w2b.y);
            atomicAdd(gp+6, w2b.z); atomicAdd(gp+7, w2b.w);
            atomicAdd(gp+8, 1.0f);
        }
        if (lo3 < TT) {
            float* gp = &sG[lo3 * CH];
            atomicAdd(gp+0, w3a.x); atomicAdd(gp+1, w3a.y);
            atomicAdd(gp+2, w3a.z); atomicAdd(gp+3, w3a.w);
            atomicAdd(gp+4, w3b.x); atomicAdd(gp+5, w3b.y);
            atomicAdd(gp+6, w3b.z); atomicAdd(gp+7, w3b.w);
            atomicAdd(gp+8, 1.0f);
        }
    }

    // wave-level packed-min reduce
    int lane = tid & 63, wv = tid >> 6;
    for (int off = 32; off > 0; off >>= 1) {
        unsigned hi32 = (unsigned)(lmin >> 32), lo32 = (unsigned)(lmin & 0xFFFFFFFFu);
        unsigned ohi = __shfl_down(hi32, off, 64);
        unsigned olo = __shfl_down(lo32, off, 64);
        ull other = ((ull)ohi << 32) | (ull)olo;
        if (other < lmin) lmin = other;
    }
    __syncthreads();                 // all LDS atomics done; sbins now dead
    if (lane == 0) ((ull*)sbins)[wv] = lmin;   // reuse sbins as 4-slot scratch
    __syncthreads();
    if (tid == 0) {
        ull m = ((ull*)sbins)[0];
        #pragma unroll
        for (int w = 1; w < 4; ++w) { ull t = ((ull*)sbins)[w]; if (t < m) m = t; }
        partMin[(size_t)p * BB + b] = m;
    }

    // writeback: part[(b*CH+c)*P + p][T] -- global coalesced over i;
    // LDS reads stride-9 (odd) -> conflict-free
    for (int c = 0; c < CH; ++c) {
        size_t gbase = (((size_t)b * CH + c) * P + p) * TT;
        for (int i = tid; i < TT; i += 256)
            part[gbase + i] = sG[i * CH + c];
    }
}

__global__ __launch_bounds__(256) void reduce_kernel(
    const float* __restrict__ part, float* __restrict__ red, int P)
{
    int idx = blockIdx.x * 256 + threadIdx.x;   // over B*CH*T = 73728
    if (idx >= BB * CH * TT) return;
    int bc = idx / TT, j = idx - bc * TT;
    const float* src = part + ((size_t)bc * P) * TT + j;
    float s = 0.f;
    for (int p = 0; p < P; ++p) s += src[(size_t)p * TT];
    red[idx] = s;                                // red layout [B][CH][T]
}

__global__ __launch_bounds__(1024) void finalize_kernel(
    const float* __restrict__ red, const ull* __restrict__ partMin,
    const float* __restrict__ wts, float* __restrict__ out, int P)
{
    int blk = blockIdx.x;
    int b = blk / FF, f = blk % FF;
    int j = threadIdx.x;
    __shared__ float buf[2][TT];
    __shared__ float scnt[TT];
    __shared__ ull smin[128];

    // parallel min over partMin[:,b]
    ull m = ~0ull;
    for (int p = j; p < P; p += 128) {
        ull t = partMin[(size_t)p * BB + b];
        if (t < m) m = t;
    }
    if (j < 128) smin[j] = m;
    __syncthreads();
    #pragma unroll
    for (int s = 64; s >= 1; s >>= 1) {
        if (j < s) { if (smin[j + s] < smin[j]) smin[j] = smin[j + s]; }
        __syncthreads();
    }
    unsigned minIdx = (unsigned)(smin[0] & 0xFFFFFFFFu);
    float wmin = wts[((size_t)b * NSQ + minIdx) * FF + f];

    // inclusive scan of counts (channel 8)
    buf[0][j] = red[((size_t)b * CH + FF) * TT + j];
    __syncthreads();
    int cur = 0;
    for (int off = 1; off < TT; off <<= 1) {
        float v = buf[cur][j];
        if (j >= off) v += buf[cur][j - off];
        buf[cur ^ 1][j] = v;
        cur ^= 1;
        __syncthreads();
    }
    scnt[j] = buf[cur][j];
    __syncthreads();

    // inclusive scan of this block's feature
    buf[0][j] = red[((size_t)b * CH + f) * TT + j];
    __syncthreads();
    cur = 0;
    for (int off = 1; off < TT; off <<= 1) {
        float v = buf[cur][j];
        if (j >= off) v += buf[cur][j - off];
        buf[cur ^ 1][j] = v;
        cur ^= 1;
        __syncthreads();
    }
    float Cj   = buf[cur][j];
    float Cjm1 = (j > 0) ? buf[cur][j - 1] : 0.f;
    float scj   = scnt[j];
    float scjm1 = (j > 0) ? scnt[j - 1] : 1.f;   // unused when j==0
    // reference quirk: idx = clip(counts-1, 0) -> counts==0 gathers
    // cumsum_w[0] == weight vector of the minimum element, not 0
    float csj   = (scj   == 0.f) ? wmin : Cj;
    float csjm1 = (j == 0) ? 0.f : ((scjm1 == 0.f) ? wmin : Cjm1);
    out[((size_t)b * TT + j) * FF + f] = csj - csjm1;
}

extern "C" void kernel_launch(void* const* d_in, const int* in_sizes, int n_in,
                              void* d_out, int out_size, void* d_ws, size_t ws_size,
                              hipStream_t stream)
{
    const float* inp  = (const float*)d_in[0];
    const float* bins = (const float*)d_in[1];
    const float* wts  = (const float*)d_in[2];
    float* out = (float*)d_out;

    // pick partial-count P (power of two) to fit workspace
    int P = 128;
    for (;;) {
        size_t need = (size_t)BB * CH * P * TT * 4   // part
                    + (size_t)BB * CH * TT * 4       // red
                    + (size_t)P * BB * 8             // partMin
                    + 1024;
        if (need <= ws_size || P == 1) break;
        P >>= 1;
    }

    char* w = (char*)d_ws;
    float* part    = (float*)w; w += (size_t)BB * CH * P * TT * 4;
    float* red     = (float*)w; w += (size_t)BB * CH * TT * 4;
    ull*   partMin = (ull*)w;

    int iters = NSQ / (P * 1024);   // elements per block = iters*1024, ILP4 per thread

    hist_kernel<<<dim3(BB * P), dim3(256), 0, stream>>>(
        inp, bins, wts, part, partMin, P, iters);
    reduce_kernel<<<dim3((BB * CH * TT + 255) / 256), dim3(256), 0, stream>>>(
        part, red, P);
    finalize_kernel<<<dim3(BB * FF), dim3(1024), 0, stream>>>(
        red, partMin, wts, out, P);
}